// Round 15
// baseline (425.686 us; speedup 1.0000x reference)
//
#include <hip/hip_runtime.h>
#include <hip/hip_bf16.h>

typedef __hip_bfloat16 bf16;
typedef __attribute__((ext_vector_type(8))) short short8v;
typedef __attribute__((ext_vector_type(4))) float f32x4;

static constexpr int Nn = 2, Hh = 256, Wd = 256;
static constexpr int Pp = Nn * Hh * Wd;  // 131072 pixels

__device__ inline void ld4(const float* p, float f[4]) {
  const float4 v = *(const float4*)p;
  f[0] = v.x; f[1] = v.y; f[2] = v.z; f[3] = v.w;
}
__device__ inline void ld4(const bf16* p, float f[4]) {
  uint2 u = *(const uint2*)p;
  f[0] = __uint_as_float(u.x << 16); f[1] = __uint_as_float(u.x & 0xffff0000u);
  f[2] = __uint_as_float(u.y << 16); f[3] = __uint_as_float(u.y & 0xffff0000u);
}
__device__ inline void st4(float* p, const float f[4]) {
  *(float4*)p = make_float4(f[0], f[1], f[2], f[3]);
}
__device__ inline void st4(bf16* p, const float f[4]) {
  union { bf16 h[4]; uint2 u; } x;
  x.h[0] = __float2bfloat16(f[0]); x.h[1] = __float2bfloat16(f[1]);
  x.h[2] = __float2bfloat16(f[2]); x.h[3] = __float2bfloat16(f[3]);
  *(uint2*)p = x.u;
}
__device__ inline uint2 pk4(float a, float b, float c, float d) {
  union { bf16 h[4]; uint2 u; } x;
  x.h[0] = __float2bfloat16(a); x.h[1] = __float2bfloat16(b);
  x.h[2] = __float2bfloat16(c); x.h[3] = __float2bfloat16(d);
  return x.u;
}
// XCD-aware swizzles (8 XCDs, h-contiguous chunks)
__device__ inline int xcd_swz2048(int phys) { return (phys & 7) * 256 + (phys >> 3); }
__device__ inline int xcd_swz1024(int phys) { return (phys & 7) * 128 + (phys >> 3); }

// ---- NCHW f32 -> NHWC f32, LDS-tiled ----
__global__ void __launch_bounds__(256) k_in_tr(const float* __restrict__ xin,
                                               float* __restrict__ X) {
  __shared__ float t[64][65];
  int blk = blockIdx.x;
  int wt = blk & 3, h = (blk >> 2) & 255, n = blk >> 10;
  int w0 = wt * 64;
  int tx = threadIdx.x & 63, ty = threadIdx.x >> 6;
  const float* src = xin + ((size_t)n * 64 * 256 + h) * 256 + w0;
#pragma unroll
  for (int cc = 0; cc < 16; cc++) {
    int c = cc * 4 + ty;
    t[c][tx] = src[(size_t)c * 65536 + tx];
  }
  __syncthreads();
  float* dst = X + (size_t)(n * 65536 + h * 256 + w0) * 64;
#pragma unroll
  for (int jj = 0; jj < 16; jj++) {
    int j = jj * 4 + ty;
    dst[(size_t)j * 64 + tx] = t[tx][j];
  }
}

// ---- NHWC f32 -> NCHW f32 ----
__global__ void __launch_bounds__(256) k_out(const float* __restrict__ X,
                                             float* __restrict__ out) {
  __shared__ float t[64][65];
  int blk = blockIdx.x;
  int wt = blk & 3, h = (blk >> 2) & 255, n = blk >> 10;
  int w0 = wt * 64;
  int tx = threadIdx.x & 63, ty = threadIdx.x >> 6;
  const float* src = X + (size_t)(n * 65536 + h * 256 + w0) * 64;
#pragma unroll
  for (int jj = 0; jj < 16; jj++) {
    int j = jj * 4 + ty;
    t[tx][j] = src[(size_t)j * 64 + tx];
  }
  __syncthreads();
  float* dst = out + ((size_t)n * 64 * 256 + h) * 256 + w0;
#pragma unroll
  for (int cc = 0; cc < 16; cc++) {
    int c = cc * 4 + ty;
    dst[(size_t)c * 65536 + tx] = t[c][tx];
  }
}

// ---- fused posconv + LN1 + QKV MFMA GEMM (XCD-swizzled, LDS-staged weights) ----
__global__ void __launch_bounds__(256) k_pcln_qkv(const float* __restrict__ X,
                                                  float* __restrict__ A,
                                                  float* __restrict__ T,
                                                  const float* __restrict__ pw,
                                                  const float* __restrict__ pb,
                                                  const float* __restrict__ g,
                                                  const float* __restrict__ b,
                                                  const bf16* __restrict__ WTq,
                                                  const float* __restrict__ qbs,
                                                  const float* __restrict__ vbias,
                                                  bf16* __restrict__ Qb,
                                                  bf16* __restrict__ Vb) {
  __shared__ float w9[9][68];
  __shared__ float bb[64];
  __shared__ bf16 yt[64][72];
  __shared__ char lw[128 * 64 * 2];
  int tid = threadIdx.x;
  for (int j = tid; j < 576; j += 256) {
    int tap = j >> 6, c = j & 63;
    w9[tap][c] = pw[c * 9 + tap];
  }
  if (tid < 64) bb[tid] = pb[tid];
  for (int ch = tid; ch < 1024; ch += 256) {
    int r = ch >> 3, cg = ch & 7;
    int byte = (r * 128 + cg * 16) ^ ((r & 7) << 4);
    *(uint4*)(lw + byte) = *(const uint4*)((const short*)WTq + ch * 8);
  }
  __syncthreads();
  int blk = xcd_swz2048(blockIdx.x);
  int gid = blk * 256 + tid;
  int cg = gid & 15, pg = gid >> 4;
  int c0 = cg << 2;
  int w0 = (pg & 63) << 2, h = (pg >> 6) & 255, n = pg >> 14;
  int pbase = (n << 16) | (h << 8) | w0;
  int pl0 = (tid >> 4) << 2;  // local pixel base (0..60)
  float acc[4][4];
  {
    const float4 b4 = *(const float4*)&bb[c0];
#pragma unroll
    for (int px = 0; px < 4; px++) {
      acc[px][0] = b4.x; acc[px][1] = b4.y; acc[px][2] = b4.z; acc[px][3] = b4.w;
    }
  }
  float xc[4][4];
#pragma unroll
  for (int ky = 0; ky < 3; ky++) {
    int hh = h + ky - 1;
    if ((unsigned)hh >= 256u) continue;
    const float* xrow = X + (size_t)((n << 16) | (hh << 8)) * 64 + c0;
    float v[6][4];
#pragma unroll
    for (int dx = 0; dx < 6; dx++) {
      int ww = w0 + dx - 1;
      if ((unsigned)ww < 256u) ld4(xrow + (size_t)ww * 64, v[dx]);
      else { v[dx][0] = 0.f; v[dx][1] = 0.f; v[dx][2] = 0.f; v[dx][3] = 0.f; }
    }
    if (ky == 1) {
#pragma unroll
      for (int px = 0; px < 4; px++)
#pragma unroll
        for (int j = 0; j < 4; j++) xc[px][j] = v[px + 1][j];
    }
#pragma unroll
    for (int kx = 0; kx < 3; kx++) {
      const float4 wv = *(const float4*)&w9[ky * 3 + kx][c0];
#pragma unroll
      for (int px = 0; px < 4; px++) {
        acc[px][0] += wv.x * v[px + kx][0]; acc[px][1] += wv.y * v[px + kx][1];
        acc[px][2] += wv.z * v[px + kx][2]; acc[px][3] += wv.w * v[px + kx][3];
      }
    }
  }
  const float4 g4 = *(const float4*)&g[c0];
  const float4 b4 = *(const float4*)&b[c0];
#pragma unroll
  for (int px = 0; px < 4; px++) {
    float a[4];
#pragma unroll
    for (int j = 0; j < 4; j++) a[j] = xc[px][j] + acc[px][j];
    st4(A + (size_t)(pbase + px) * 64 + c0, a);
    float s = a[0] + a[1] + a[2] + a[3];
#pragma unroll
    for (int off = 8; off; off >>= 1) s += __shfl_xor(s, off);
    float mean = s * (1.f / 64.f);
    float d[4], q = 0.f;
#pragma unroll
    for (int j = 0; j < 4; j++) { d[j] = a[j] - mean; q += d[j] * d[j]; }
#pragma unroll
    for (int off = 8; off; off >>= 1) q += __shfl_xor(q, off);
    float inv = rsqrtf(q * (1.f / 64.f) + 1e-6f);
    float y[4] = {d[0] * inv * g4.x + b4.x, d[1] * inv * g4.y + b4.y,
                  d[2] * inv * g4.z + b4.z, d[3] * inv * g4.w + b4.w};
    st4(T + (size_t)(pbase + px) * 64 + c0, y);
    st4(&yt[pl0 + px][c0], y);
  }
  __syncthreads();
  // QKV MFMA: tile base is block-uniform blk*64
  int wid = tid >> 6, lane = tid & 63;
  int lr = lane & 15, lg = lane >> 4;
  size_t mbase = (size_t)blk * 64;
  short8v a0 = *(const short8v*)&yt[wid * 16 + lr][lg * 8];
  short8v a1 = *(const short8v*)&yt[wid * 16 + lr][32 + lg * 8];
#pragma unroll
  for (int nt = 0; nt < 8; nt++) {
    int col = nt * 16 + lr;
    float bv = col < 64 ? qbs[col] : vbias[col - 64];
    f32x4 acc4 = {bv, bv, bv, bv};
    int byte = (col * 128 + lg * 16) ^ ((col & 7) << 4);
    acc4 = __builtin_amdgcn_mfma_f32_16x16x32_bf16(a0, *(const short8v*)(lw + byte), acc4, 0, 0, 0);
    byte = (col * 128 + 64 + lg * 16) ^ ((col & 7) << 4);
    acc4 = __builtin_amdgcn_mfma_f32_16x16x32_bf16(a1, *(const short8v*)(lw + byte), acc4, 0, 0, 0);
#pragma unroll
    for (int j = 0; j < 4; j++) {
      size_t pix = mbase + wid * 16 + lg * 4 + j;
      if (col < 64) Qb[pix * 64 + col] = __float2bfloat16(acc4[j]);
      else          Vb[pix * 64 + (col - 64)] = __float2bfloat16(acc4[j]);
    }
  }
}

// ---- merged weight prep ----
__global__ void k_prep(const float* __restrict__ qkvw, const float* __restrict__ qkvb,
                       const float* __restrict__ wow, const float* __restrict__ f2w,
                       const float* __restrict__ f1w, const float* __restrict__ f1b,
                       const float* __restrict__ pww,
                       bf16* __restrict__ WTq, bf16* __restrict__ WTo,
                       bf16* __restrict__ WT2, bf16* __restrict__ WTf1,
                       float* __restrict__ qbs, float* __restrict__ bc) {
  int t = blockIdx.x * 256 + threadIdx.x;
  if (t < 8192) {
    int r = t >> 6, k = t & 63;
    int src = r < 64 ? r : r + 64;
    float v = qkvw[k * 192 + src];
    if (r < 64) v *= 0.125f;
    WTq[t] = __float2bfloat16(v);
  } else if (t < 12288) {
    int t2 = t - 8192;
    int r = t2 >> 6, k = t2 & 63;
    WTo[t2] = __float2bfloat16(wow[k * 64 + r]);
  } else if (t < 20480) {
    int t2 = t - 12288;
    int r = t2 >> 7, k = t2 & 127;
    WT2[t2] = __float2bfloat16(f2w[k * 64 + r]);
  } else if (t < 28672) {
    int t2 = t - 20480;                    // WTf1 rows 0..127 = W1b^T
    int r = t2 >> 6, k = t2 & 63;
    WTf1[t2] = __float2bfloat16(f1w[k * 256 + 128 + r]);
  } else if (t < 36864) {                  // WTf1 rows 128..255 = (W1a@pw^T)^T
    int t2 = t - 28672;
    int o = t2 & 127, k = t2 >> 7;
    float acc = 0.f;
    for (int j = 0; j < 128; j++) acc += f1w[k * 256 + j] * pww[o * 128 + j];
    WTf1[(128 + o) * 64 + k] = __float2bfloat16(acc);
  } else if (t < 36992) {                  // bc = b1a @ pw^T
    int o = t - 36864;
    float bv = 0.f;
    for (int j = 0; j < 128; j++) bv += f1b[j] * pww[o * 128 + j];
    bc[o] = bv;
  }
  if (t < 64) qbs[t] = qkvb[t] * 0.125f;
}

// ---- fused wo GEMM + res + LN2 + FC1 GEMM (LDS-staged weights) ----
__global__ void __launch_bounds__(256) k_wo_ln_fc1(const bf16* __restrict__ In,
                                                   const bf16* __restrict__ WTo,
                                                   const float* __restrict__ wob,
                                                   const float* __restrict__ Res,
                                                   float* __restrict__ Xo,
                                                   const float* __restrict__ g,
                                                   const float* __restrict__ b,
                                                   const bf16* __restrict__ WTf1,
                                                   const float* __restrict__ b1,
                                                   const float* __restrict__ b2,
                                                   bf16* __restrict__ VH,
                                                   bf16* __restrict__ PWO) {
  __shared__ char lwo[64 * 64 * 2];
  __shared__ char lf1[256 * 64 * 2];
  __shared__ float xs[16][68];
  __shared__ bf16 a2t[16][72];
  int tid = threadIdx.x;
  for (int ch = tid; ch < 512; ch += 256) {
    int r = ch >> 3, cg = ch & 7;
    int byte = (r * 128 + cg * 16) ^ ((r & 7) << 4);
    *(uint4*)(lwo + byte) = *(const uint4*)((const short*)WTo + ch * 8);
  }
  for (int ch = tid; ch < 2048; ch += 256) {
    int r = ch >> 3, cg = ch & 7;
    int byte = (r * 128 + cg * 16) ^ ((r & 7) << 4);
    *(uint4*)(lf1 + byte) = *(const uint4*)((const short*)WTf1 + ch * 8);
  }
  __syncthreads();
  int wid = tid >> 6, lane = tid & 63;
  int lr = lane & 15, lg = lane >> 4;
  int col_o = wid * 16 + lr;
  int mb = blockIdx.x * 128;
  int row2 = tid >> 4, cq = (tid & 15) << 2;
  const float4 g4 = *(const float4*)&g[cq];
  const float4 b4 = *(const float4*)&b[cq];
  float bvo = wob[col_o];
  for (int ms = 0; ms < 8; ms++) {
    int m0 = mb + ms * 16;
    {
      short8v a0 = *(const short8v*)((const short*)In + (size_t)(m0 + lr) * 64 + lg * 8);
      short8v a1 = *(const short8v*)((const short*)In + (size_t)(m0 + lr) * 64 + 32 + lg * 8);
      f32x4 acc = {bvo, bvo, bvo, bvo};
      int byte = (col_o * 128 + lg * 16) ^ ((col_o & 7) << 4);
      acc = __builtin_amdgcn_mfma_f32_16x16x32_bf16(a0, *(const short8v*)(lwo + byte), acc, 0, 0, 0);
      byte = (col_o * 128 + 64 + lg * 16) ^ ((col_o & 7) << 4);
      acc = __builtin_amdgcn_mfma_f32_16x16x32_bf16(a1, *(const short8v*)(lwo + byte), acc, 0, 0, 0);
#pragma unroll
      for (int j = 0; j < 4; j++) {
        float v = acc[j] + Res[(size_t)(m0 + lg * 4 + j) * 64 + col_o];
        Xo[(size_t)(m0 + lg * 4 + j) * 64 + col_o] = v;
        xs[lg * 4 + j][col_o] = v;
      }
    }
    __syncthreads();
    {
      float a4[4] = {xs[row2][cq], xs[row2][cq + 1], xs[row2][cq + 2], xs[row2][cq + 3]};
      float s = a4[0] + a4[1] + a4[2] + a4[3];
#pragma unroll
      for (int off = 8; off; off >>= 1) s += __shfl_xor(s, off);
      float mean = s * (1.f / 64.f);
      float d[4], q = 0.f;
#pragma unroll
      for (int j = 0; j < 4; j++) { d[j] = a4[j] - mean; q += d[j] * d[j]; }
#pragma unroll
      for (int off = 8; off; off >>= 1) q += __shfl_xor(q, off);
      float inv = rsqrtf(q * (1.f / 64.f) + 1e-6f);
      float y[4] = {d[0] * inv * g4.x + b4.x, d[1] * inv * g4.y + b4.y,
                    d[2] * inv * g4.z + b4.z, d[3] * inv * g4.w + b4.w};
      st4(&a2t[row2][cq], y);
    }
    __syncthreads();
    {
      short8v f0 = *(const short8v*)&a2t[lr][lg * 8];
      short8v f1 = *(const short8v*)&a2t[lr][32 + lg * 8];
#pragma unroll
      for (int t = 0; t < 4; t++) {
        int nt = wid * 4 + t;
        int col = nt * 16 + lr;
        float bv = col < 128 ? b1[col] : b2[col - 128];
        f32x4 acc = {bv, bv, bv, bv};
        int byte = (col * 128 + lg * 16) ^ ((col & 7) << 4);
        acc = __builtin_amdgcn_mfma_f32_16x16x32_bf16(f0, *(const short8v*)(lf1 + byte), acc, 0, 0, 0);
        byte = (col * 128 + 64 + lg * 16) ^ ((col & 7) << 4);
        acc = __builtin_amdgcn_mfma_f32_16x16x32_bf16(f1, *(const short8v*)(lf1 + byte), acc, 0, 0, 0);
#pragma unroll
        for (int j = 0; j < 4; j++) {
          size_t pix = m0 + lg * 4 + j;
          if (col < 128) VH[pix * 128 + col] = __float2bfloat16(acc[j]);
          else           PWO[pix * 128 + (col - 128)] = __float2bfloat16(acc[j]);
        }
      }
    }
    __syncthreads();
  }
}

// ---- fused GLU-dw + gelu*VH + fc2 GEMM + residual ----
// 128-px blocks, XCD-swizzled, gt XOR-swizzled [128][128] (LDS < 54.6KB -> 3 blk/CU)
__global__ void __launch_bounds__(256) k_glu_fc2(const bf16* __restrict__ PWO,
                                                 const bf16* __restrict__ VH,
                                                 const float* __restrict__ wt,
                                                 const float* __restrict__ bs,
                                                 const bf16* __restrict__ WT2,
                                                 const float* __restrict__ f2b,
                                                 float* __restrict__ X) {
  __shared__ float wd[9][132];
  __shared__ float bb[128];
  __shared__ char gts[128 * 256];   // gt[128][128] bf16, XOR-swizzled
  __shared__ char lw2[64 * 128 * 2];
  int tid = threadIdx.x;
  for (int j = tid; j < 1152; j += 256) {
    int tap = j >> 7, c = j & 127;
    wd[tap][c] = wt[c * 9 + tap];
  }
  if (tid < 128) bb[tid] = bs[tid];
  for (int ch = tid; ch < 1024; ch += 256) {
    int r = ch >> 4, cg = ch & 15;
    int byte = (r * 256 + cg * 16) ^ ((r & 7) << 4);
    *(uint4*)(lw2 + byte) = *(const uint4*)((const short*)WT2 + ch * 8);
  }
  __syncthreads();
  int blk = xcd_swz1024(blockIdx.x);  // 1024 = (n*256 + h)*2 + half
  int w0 = (blk & 1) * 128, h = (blk >> 1) & 255, n = blk >> 9;
  int pbase = (n << 16) | (h << 8) | w0;
  int cg = tid & 31, c0 = cg << 2;
  int pg = tid >> 5;               // 0..7
  const float4 bb4 = *(const float4*)&bb[c0];
#pragma unroll
  for (int pass = 0; pass < 4; pass++) {
    int wb = w0 + pass * 32 + pg * 4;  // this thread's 4-px base
    // prefetch VH early (independent of conv chain)
    float vh[4][4];
#pragma unroll
    for (int px = 0; px < 4; px++)
      ld4(VH + (size_t)(pbase + pass * 32 + pg * 4 + px) * 128 + c0, vh[px]);
    float acc[4][4];
#pragma unroll
    for (int px = 0; px < 4; px++) {
      acc[px][0] = bb4.x; acc[px][1] = bb4.y; acc[px][2] = bb4.z; acc[px][3] = bb4.w;
    }
#pragma unroll
    for (int ky = 0; ky < 3; ky++) {
      int hh = h + ky - 1;
      if ((unsigned)hh >= 256u) continue;
      const bf16* prow = PWO + (size_t)((n << 16) | (hh << 8)) * 128 + c0;
      float v[6][4];
#pragma unroll
      for (int dx = 0; dx < 6; dx++) {
        int ww = wb + dx - 1;
        if ((unsigned)ww < 256u) ld4(prow + (size_t)ww * 128, v[dx]);
        else { v[dx][0] = 0.f; v[dx][1] = 0.f; v[dx][2] = 0.f; v[dx][3] = 0.f; }
      }
#pragma unroll
      for (int kx = 0; kx < 3; kx++) {
        const float4 wv = *(const float4*)&wd[ky * 3 + kx][c0];
#pragma unroll
        for (int px = 0; px < 4; px++) {
          acc[px][0] += wv.x * v[px + kx][0]; acc[px][1] += wv.y * v[px + kx][1];
          acc[px][2] += wv.z * v[px + kx][2]; acc[px][3] += wv.w * v[px + kx][3];
        }
      }
    }
#pragma unroll
    for (int px = 0; px < 4; px++) {
      int pl = pass * 32 + pg * 4 + px;
      float o[4];
#pragma unroll
      for (int j = 0; j < 4; j++) {
        float x = acc[px][j];
        float ge = 0.5f * x * (1.f + erff(x * 0.70710678118f));
        o[j] = ge * vh[px][j];
      }
      int byte = (pl * 256 + c0 * 2) ^ ((pl & 7) << 4);
      st4((bf16*)(gts + byte), o);
    }
  }
  __syncthreads();
  // fc2: K=128, N=64; 8 m-tiles, wave handles m-tiles {wid, wid+4}
  int wid = tid >> 6, lane = tid & 63;
  int lr = lane & 15, lg = lane >> 4;
#pragma unroll
  for (int mi = 0; mi < 2; mi++) {
    int mt = wid + mi * 4;
    int m0 = mt * 16;
    short8v a[4];
#pragma unroll
    for (int ks = 0; ks < 4; ks++) {
      int row = m0 + lr;
      int byte = (row * 256 + ks * 64 + lg * 16) ^ ((row & 7) << 4);
      a[ks] = *(const short8v*)(gts + byte);
    }
#pragma unroll
    for (int nt = 0; nt < 4; nt++) {
      int col = nt * 16 + lr;
      float bv = f2b[col];
      f32x4 acc = {bv, bv, bv, bv};
#pragma unroll
      for (int ks = 0; ks < 4; ks++) {
        int byte = (col * 256 + ks * 64 + lg * 16) ^ ((col & 7) << 4);
        acc = __builtin_amdgcn_mfma_f32_16x16x32_bf16(a[ks], *(const short8v*)(lw2 + byte), acc, 0, 0, 0);
      }
#pragma unroll
      for (int j = 0; j < 4; j++) {
        size_t pix = pbase + m0 + lg * 4 + j;
        X[pix * 64 + col] += acc[j];
      }
    }
  }
}

// ---- 8x8 block means of LN1 (f32, exact routing path) ----
__global__ void k_pool8(const float* __restrict__ T, float* __restrict__ Y8) {
  int b = blockIdx.x;
  int c = threadIdx.x;
  int bx = b & 31, by = (b >> 5) & 31, n = b >> 10;
  float acc = 0.f;
  for (int r = 0; r < 8; r++)
    for (int s = 0; s < 8; s++) {
      int p = (n << 16) | ((by * 8 + r) << 8) | (bx * 8 + s);
      acc += T[(size_t)p * 64 + c];
    }
  Y8[(size_t)b * 64 + c] = acc * (1.f / 64.f);
}

// ---- fused window-mean + q/k projection ----
__global__ void __launch_bounds__(256) k_qkwin2(const float* __restrict__ Y8,
                                                const float* __restrict__ qw,
                                                const float* __restrict__ qb,
                                                float* __restrict__ QW,
                                                float* __restrict__ KW) {
  __shared__ float ym[4][68];
  int blk = blockIdx.x;
  int sel = blk >> 5;
  int r0 = (blk & 31) * 4;
  int tid = threadIdx.x;
  {
    int rl = tid >> 6, c = tid & 63;
    int row = r0 + rl;
    int n = row >> 6, win = row & 63;
    int wi = win >> 3, wj = win & 7;
    float acc = 0.f;
    for (int ti = 0; ti < 4; ti++)
      for (int tj = 0; tj < 4; tj++) {
        int y8 = (n * 32 + wi * 4 + ti) * 32 + wj * 4 + tj;
        acc += Y8[(size_t)y8 * 64 + c];
      }
    ym[rl][c] = acc * (1.f / 16.f);
  }
  __syncthreads();
  int rl = tid >> 6, c = tid & 63;
  int row = r0 + rl;
  int colg = sel * 64 + c;
  float acc = qb[colg];
  for (int k = 0; k < 64; k++) acc += ym[rl][k] * qw[k * 192 + colg];
  (sel ? KW : QW)[(size_t)row * 64 + c] = acc;
}

__global__ void k_kvp(const float* __restrict__ Y8, const float* __restrict__ qw,
                      const float* __restrict__ qb, float* __restrict__ KVP) {
  int t = blockIdx.x * blockDim.x + threadIdx.x;
  if (t >= 262144) return;
  int c2 = t & 127, tok = (t >> 7) & 15, win = (t >> 11) & 63, n = t >> 17;
  int wi = win >> 3, wj = win & 7, ti = tok >> 2, tj = tok & 3;
  int y8 = (n * 32 + wi * 4 + ti) * 32 + wj * 4 + tj;
  const float* y = Y8 + (size_t)y8 * 64;
  int col = 64 + c2;
  float acc = qb[col];
  for (int k = 0; k < 64; k++) acc += y[k] * qw[k * 192 + col];
  KVP[t] = acc;
}

// ---- routing: top-4 ----
__global__ void __launch_bounds__(64) k_route(const float* __restrict__ QW,
                                              const float* __restrict__ KW,
                                              int* __restrict__ RIDX) {
  __shared__ float kk[64][65];
  __shared__ float qq[64];
  int b = blockIdx.x;
  int lane = threadIdx.x;
  int n = b >> 6;
  qq[lane] = QW[(size_t)b * 64 + lane];
  for (int r = 0; r < 64; r++) kk[r][lane] = KW[(size_t)(n * 64 + r) * 64 + lane];
  __syncthreads();
  float t = 0.f;
  for (int c = 0; c < 64; c++) t += qq[c] * kk[lane][c];
  t *= 0.125f;
  int o0 = 0, o1 = 0, o2 = 0, o3 = 0;
#pragma unroll
  for (int j = 0; j < 4; j++) {
    float v = t; int idx = lane;
#pragma unroll
    for (int off = 32; off; off >>= 1) {
      float ov = __shfl_xor(v, off);
      int oi = __shfl_xor(idx, off);
      if (ov > v || (ov == v && oi < idx)) { v = ov; idx = oi; }
    }
    if (j == 0) o0 = idx; else if (j == 1) o1 = idx;
    else if (j == 2) o2 = idx; else o3 = idx;
    if (lane == idx) t = -1e30f;
  }
  if (lane == 0) {
    int* o = RIDX + (size_t)b * 4;
    o[0] = o0; o[1] = o1; o[2] = o2; o[3] = o3;
  }
}

// ---- MFMA attention -> bf16 output ----
__global__ void __launch_bounds__(256) k_attn_mf(const bf16* __restrict__ Qb,
                                                 const float* __restrict__ KVP,
                                                 const int* __restrict__ RIDX,
                                                 bf16* __restrict__ Sbf) {
  __shared__ bf16 ks[64][72];
  __shared__ bf16 vt[64][72];
  __shared__ bf16 pa[4][16][72];
  __shared__ float ldn[4][16];
  __shared__ int idx[4];
  int blk = blockIdx.x;
  int part = blk & 3, bw = blk >> 2;
  int n = bw >> 6, win = bw & 63;
  int tid = threadIdx.x;
  if (tid < 4) idx[tid] = RIDX[bw * 4 + tid];
  __syncthreads();
  {
    int tok = tid & 63;
    const float* src = KVP + ((size_t)(n * 64 + idx[tok >> 4]) * 16 + (tok & 15)) * 128;
    for (int cq = tid >> 6; cq < 16; cq += 4) {
      int c0 = cq * 4;
      const float4 k4 = *(const float4*)&src[c0];
      *(uint2*)&ks[tok][c0] = pk4(k4.x, k4.y, k4.z, k4.w);
      const float4 v4 = *(const float4*)&src[64 + c0];
      vt[c0 + 0][tok] = __float2bfloat16(v4.x);
      vt[c0 + 1][tok] = __float2bfloat16(v4.y);
      vt[c0 + 2][tok] = __float2bfloat16(v4.z);
      vt[c0 + 3][tok] = __float2bfloat16(v4.w);
    }
  }
  __syncthreads();
  int w = tid >> 6, lane = tid & 63;
  int lr = lane & 15, lg = lane >> 4;
  int wi = win >> 3, wj = win & 7;
  for (int it = 0; it < 4; it++) {
    int qbase = part * 256 + w * 64 + it * 16;
    int q_b = qbase + lr;
    int pix_b = (n << 16) | ((wi * 32 + (q_b >> 5)) << 8) | (wj * 32 + (q_b & 31));
    short8v qf0 = *(const short8v*)((const short*)Qb + (size_t)pix_b * 64 + lg * 8);
    short8v qf1 = *(const short8v*)((const short*)Qb + (size_t)pix_b * 64 + 32 + lg * 8);
    f32x4 p[4] = {{0,0,0,0},{0,0,0,0},{0,0,0,0},{0,0,0,0}};
#pragma unroll
    for (int mt = 0; mt < 4; mt++) {
      short8v a0 = *(const short8v*)&ks[mt * 16 + lr][lg * 8];
      p[mt] = __builtin_amdgcn_mfma_f32_16x16x32_bf16(a0, qf0, p[mt], 0, 0, 0);
    }
#pragma unroll
    for (int mt = 0; mt < 4; mt++) {
      short8v a1 = *(const short8v*)&ks[mt * 16 + lr][32 + lg * 8];
      p[mt] = __builtin_amdgcn_mfma_f32_16x16x32_bf16(a1, qf1, p[mt], 0, 0, 0);
    }
    float mx = -1e30f;
#pragma unroll
    for (int mt = 0; mt < 4; mt++)
#pragma unroll
      for (int j = 0; j < 4; j++) mx = fmaxf(mx, p[mt][j]);
    mx = fmaxf(mx, __shfl_xor(mx, 16));
    mx = fmaxf(mx, __shfl_xor(mx, 32));
    float e[4][4];
    float sum = 0.f;
#pragma unroll
    for (int mt = 0; mt < 4; mt++)
#pragma unroll
      for (int j = 0; j < 4; j++) { e[mt][j] = __expf(p[mt][j] - mx); sum += e[mt][j]; }
    sum += __shfl_xor(sum, 16);
    sum += __shfl_xor(sum, 32);
    if (lg == 0) ldn[w][lr] = sum;
#pragma unroll
    for (int mt = 0; mt < 4; mt++)
      *(uint2*)&pa[w][lr][mt * 16 + lg * 4] = pk4(e[mt][0], e[mt][1], e[mt][2], e[mt][3]);
    short8v pf0 = *(const short8v*)&pa[w][lr][lg * 8];
    short8v pf1 = *(const short8v*)&pa[w][lr][32 + lg * 8];
    f32x4 o4[4] = {{0,0,0,0},{0,0,0,0},{0,0,0,0},{0,0,0,0}};
#pragma unroll
    for (int nt = 0; nt < 4; nt++) {
      short8v v0 = *(const short8v*)&vt[nt * 16 + lr][lg * 8];
      o4[nt] = __builtin_amdgcn_mfma_f32_16x16x32_bf16(pf0, v0, o4[nt], 0, 0, 0);
    }
#pragma unroll
    for (int nt = 0; nt < 4; nt++) {
      short8v v1 = *(const short8v*)&vt[nt * 16 + lr][32 + lg * 8];
      o4[nt] = __builtin_amdgcn_mfma_f32_16x16x32_bf16(pf1, v1, o4[nt], 0, 0, 0);
    }
    float linv[4];
#pragma unroll
    for (int j = 0; j < 4; j++) linv[j] = 1.f / ldn[w][lg * 4 + j];
#pragma unroll
    for (int j = 0; j < 4; j++) {
      int q_o = qbase + lg * 4 + j;
      size_t pix_o = (n << 16) | ((wi * 32 + (q_o >> 5)) << 8) | (wj * 32 + (q_o & 31));
      bf16* op = Sbf + pix_o * 64 + lr;
#pragma unroll
      for (int nt = 0; nt < 4; nt++) op[nt * 16] = __float2bfloat16(o4[nt][j] * linv[j]);
    }
  }
}

// ---- LePE: 4 px/thread (XCD-swizzled); Sb = bf16(Sbf + dw5x5(V)) ----
__global__ void __launch_bounds__(256) k_lepe4(const bf16* __restrict__ V,
                                               const bf16* __restrict__ Sbf,
                                               bf16* __restrict__ Sb,
                                               const float* __restrict__ wt,
                                               const float* __restrict__ bs) {
  __shared__ float w5[25][68];
  __shared__ float bb[64];
  int tid = threadIdx.x;
  for (int j = tid; j < 1600; j += 256) {
    int tap = j >> 6, c = j & 63;
    w5[tap][c] = wt[c * 25 + tap];
  }
  if (tid < 64) bb[tid] = bs[tid];
  __syncthreads();
  int blk = xcd_swz2048(blockIdx.x);
  int gid = blk * 256 + tid;
  int cg = gid & 15, pg = gid >> 4;
  int c0 = cg << 2;
  int w0 = (pg & 63) << 2, h = (pg >> 6) & 255, n = pg >> 14;
  int pbase = (n << 16) | (h << 8) | w0;
  float acc[4][4];
  {
    const float4 b4 = *(const float4*)&bb[c0];
#pragma unroll
    for (int px = 0; px < 4; px++) {
      acc[px][0] = b4.x; acc[px][1] = b4.y; acc[px][2] = b4.z; acc[px][3] = b4.w;
    }
  }
#pragma unroll
  for (int ky = 0; ky < 5; ky++) {
    int hh = h + ky - 2;
    if ((unsigned)hh >= 256u) continue;
    const bf16* vrow = V + (size_t)((n << 16) | (hh << 8)) * 64 + c0;
    float v[8][4];
#pragma unroll
    for (int dx = 0; dx < 8; dx++) {
      int ww = w0 + dx - 2;
      if ((unsigned)ww < 256u) ld4(vrow + (size_t)ww * 64, v[dx]);
      else { v[dx][0] = 0.f; v[dx][1] = 0.f; v[dx][2] = 0.f; v[dx][3] = 0.f; }
    }
#pragma unroll
    for (int kx = 0; kx < 5; kx++) {
      const float4 wv = *(const float4*)&w5[ky * 5 + kx][c0];
#pragma unroll
      for (int px = 0; px < 4; px++) {
        acc[px][0] += wv.x * v[px + kx][0]; acc[px][1] += wv.y * v[px + kx][1];
        acc[px][2] += wv.z * v[px + kx][2]; acc[px][3] += wv.w * v[px + kx][3];
      }
    }
  }
#pragma unroll
  for (int px = 0; px < 4; px++) {
    float s4[4];
    ld4(Sbf + (size_t)(pbase + px) * 64 + c0, s4);
    float o[4] = {s4[0] + acc[px][0], s4[1] + acc[px][1],
                  s4[2] + acc[px][2], s4[3] + acc[px][3]};
    st4(Sb + (size_t)(pbase + px) * 64 + c0, o);
  }
}

extern "C" void kernel_launch(void* const* d_in, const int* in_sizes, int n_in,
                              void* d_out, int out_size, void* d_ws, size_t ws_size,
                              hipStream_t stream) {
  (void)in_sizes; (void)n_in; (void)out_size; (void)ws_size;
  const float* xin = (const float*)d_in[0];
  auto Wp = [&](int i) { return (const float*)d_in[i]; };
  char* ws = (char*)d_ws;
  const size_t MB = 1u << 20;
  float* X  = (float*)(ws + 0 * MB);
  float* A  = (float*)(ws + 32 * MB);
  float* T  = (float*)(ws + 64 * MB);
  char*  sm = ws + 128 * MB;
  size_t off = 0;
  auto alloc = [&](size_t bytes) {
    void* p = sm + off;
    off += (bytes + 255) & ~(size_t)255;
    return p;
  };
  float* Y8   = (float*)alloc(2 * 32 * 32 * 64 * 4);
  float* QW   = (float*)alloc(2 * 64 * 64 * 4);
  float* KW   = (float*)alloc(2 * 64 * 64 * 4);
  float* KVP  = (float*)alloc(2 * 64 * 16 * 128 * 4);
  int*  RIDX  = (int*)alloc(2 * 64 * 4 * 4);
  float* bc   = (float*)alloc(128 * 4);
  bf16* WTq   = (bf16*)alloc(128 * 64 * 2);
  bf16* WTo   = (bf16*)alloc(64 * 64 * 2);
  bf16* WT2   = (bf16*)alloc(64 * 128 * 2);
  bf16* WTf1  = (bf16*)alloc(256 * 64 * 2);
  float* qbs  = (float*)alloc(64 * 4);
  bf16* Vb   = (bf16*)(ws + 96 * MB);    // [P][64]
  bf16* Qb   = (bf16*)(ws + 112 * MB);   // [P][64]
  bf16* Sbf  = (bf16*)T;                 // [P][64]
  bf16* Sb   = (bf16*)(ws + 112 * MB);   // [P][64] (Qb dead after attn)
  bf16* VH   = (bf16*)A;                 // [P][128] (A consumed in-kernel)
  bf16* PWO  = (bf16*)T;                 // [P][128] (T/Sbf dead)

  k_in_tr<<<dim3(2048), dim3(256), 0, stream>>>(xin, X);
  for (int i = 0; i < 2; i++) {
    const float *posw = Wp(1) + i * 64 * 9, *posb = Wp(2) + i * 64;
    const float *l1g = Wp(3) + i * 64, *l1b = Wp(4) + i * 64;
    const float *qkvw = Wp(5) + i * 64 * 192, *qkvb = Wp(6) + i * 192;
    const float *lpw = Wp(7) + i * 64 * 25, *lpb = Wp(8) + i * 64;
    const float *wow = Wp(9) + i * 64 * 64, *wob = Wp(10) + i * 64;
    const float *l2g = Wp(11) + i * 64, *l2b = Wp(12) + i * 64;
    const float *f1w = Wp(13) + i * 64 * 256, *f1b = Wp(14) + i * 256;
    const float *pww = Wp(15) + i * 128 * 128;
    const float *dww = Wp(16) + i * 128 * 9, *dwb = Wp(17) + i * 128;
    const float *f2w = Wp(18) + i * 128 * 64, *f2b = Wp(19) + i * 64;

    k_prep<<<dim3(145), dim3(256), 0, stream>>>(qkvw, qkvb, wow, f2w, f1w, f1b, pww,
                                                WTq, WTo, WT2, WTf1, qbs, bc);
    k_pcln_qkv<<<dim3(2048), dim3(256), 0, stream>>>(
        X, A, T, posw, posb, l1g, l1b, WTq, qbs, qkvb + 128, Qb, Vb);
    k_pool8<<<dim3(2048), dim3(64), 0, stream>>>(T, Y8);
    k_qkwin2<<<dim3(64), dim3(256), 0, stream>>>(Y8, qkvw, qkvb, QW, KW);
    k_kvp<<<dim3(1024), dim3(256), 0, stream>>>(Y8, qkvw, qkvb, KVP);
    k_route<<<dim3(128), dim3(64), 0, stream>>>(QW, KW, RIDX);
    k_attn_mf<<<dim3(512), dim3(256), 0, stream>>>(Qb, KVP, RIDX, Sbf);
    k_lepe4<<<dim3(2048), dim3(256), 0, stream>>>(Vb, Sbf, Sb, lpw, lpb);
    k_wo_ln_fc1<<<dim3(Pp / 128), dim3(256), 0, stream>>>(
        Sb, WTo, wob, A, X, l2g, l2b, WTf1, f1b + 128, bc, VH, PWO);
    k_glu_fc2<<<dim3(1024), dim3(256), 0, stream>>>(PWO, VH, dww, dwb, WT2, f2b, X);
  }
  k_out<<<dim3(2048), dim3(256), 0, stream>>>(X, (float*)d_out);
}

// Round 16
// 418.839 us; speedup vs baseline: 1.0163x; 1.0163x over previous
//
#include <hip/hip_runtime.h>
#include <hip/hip_bf16.h>

typedef __hip_bfloat16 bf16;
typedef __attribute__((ext_vector_type(8))) short short8v;
typedef __attribute__((ext_vector_type(4))) float f32x4;

static constexpr int Nn = 2, Hh = 256, Wd = 256;
static constexpr int Pp = Nn * Hh * Wd;  // 131072 pixels

__device__ inline void ld4(const float* p, float f[4]) {
  const float4 v = *(const float4*)p;
  f[0] = v.x; f[1] = v.y; f[2] = v.z; f[3] = v.w;
}
__device__ inline void ld4(const bf16* p, float f[4]) {
  uint2 u = *(const uint2*)p;
  f[0] = __uint_as_float(u.x << 16); f[1] = __uint_as_float(u.x & 0xffff0000u);
  f[2] = __uint_as_float(u.y << 16); f[3] = __uint_as_float(u.y & 0xffff0000u);
}
__device__ inline void st4(float* p, const float f[4]) {
  *(float4*)p = make_float4(f[0], f[1], f[2], f[3]);
}
__device__ inline void st4(bf16* p, const float f[4]) {
  union { bf16 h[4]; uint2 u; } x;
  x.h[0] = __float2bfloat16(f[0]); x.h[1] = __float2bfloat16(f[1]);
  x.h[2] = __float2bfloat16(f[2]); x.h[3] = __float2bfloat16(f[3]);
  *(uint2*)p = x.u;
}
__device__ inline uint2 pk4(float a, float b, float c, float d) {
  union { bf16 h[4]; uint2 u; } x;
  x.h[0] = __float2bfloat16(a); x.h[1] = __float2bfloat16(b);
  x.h[2] = __float2bfloat16(c); x.h[3] = __float2bfloat16(d);
  return x.u;
}
// XCD-aware swizzles (8 XCDs, h-contiguous chunks)
__device__ inline int xcd_swz2048(int phys) { return (phys & 7) * 256 + (phys >> 3); }
__device__ inline int xcd_swz1024(int phys) { return (phys & 7) * 128 + (phys >> 3); }

// ---- NCHW f32 -> NHWC f32, LDS-tiled ----
__global__ void __launch_bounds__(256) k_in_tr(const float* __restrict__ xin,
                                               float* __restrict__ X) {
  __shared__ float t[64][65];
  int blk = blockIdx.x;
  int wt = blk & 3, h = (blk >> 2) & 255, n = blk >> 10;
  int w0 = wt * 64;
  int tx = threadIdx.x & 63, ty = threadIdx.x >> 6;
  const float* src = xin + ((size_t)n * 64 * 256 + h) * 256 + w0;
#pragma unroll
  for (int cc = 0; cc < 16; cc++) {
    int c = cc * 4 + ty;
    t[c][tx] = src[(size_t)c * 65536 + tx];
  }
  __syncthreads();
  float* dst = X + (size_t)(n * 65536 + h * 256 + w0) * 64;
#pragma unroll
  for (int jj = 0; jj < 16; jj++) {
    int j = jj * 4 + ty;
    dst[(size_t)j * 64 + tx] = t[tx][j];
  }
}

// ---- NHWC f32 -> NCHW f32 ----
__global__ void __launch_bounds__(256) k_out(const float* __restrict__ X,
                                             float* __restrict__ out) {
  __shared__ float t[64][65];
  int blk = blockIdx.x;
  int wt = blk & 3, h = (blk >> 2) & 255, n = blk >> 10;
  int w0 = wt * 64;
  int tx = threadIdx.x & 63, ty = threadIdx.x >> 6;
  const float* src = X + (size_t)(n * 65536 + h * 256 + w0) * 64;
#pragma unroll
  for (int jj = 0; jj < 16; jj++) {
    int j = jj * 4 + ty;
    t[tx][j] = src[(size_t)j * 64 + tx];
  }
  __syncthreads();
  float* dst = out + ((size_t)n * 64 * 256 + h) * 256 + w0;
#pragma unroll
  for (int cc = 0; cc < 16; cc++) {
    int c = cc * 4 + ty;
    dst[(size_t)c * 65536 + tx] = t[c][tx];
  }
}

// ---- fused posconv + LN1 + QKV MFMA GEMM (XCD-swizzled, LDS-staged weights) ----
__global__ void __launch_bounds__(256) k_pcln_qkv(const float* __restrict__ X,
                                                  float* __restrict__ A,
                                                  float* __restrict__ T,
                                                  const float* __restrict__ pw,
                                                  const float* __restrict__ pb,
                                                  const float* __restrict__ g,
                                                  const float* __restrict__ b,
                                                  const bf16* __restrict__ WTq,
                                                  const float* __restrict__ qbs,
                                                  const float* __restrict__ vbias,
                                                  bf16* __restrict__ Qb,
                                                  bf16* __restrict__ Vb) {
  __shared__ float w9[9][68];
  __shared__ float bb[64];
  __shared__ bf16 yt[64][72];
  __shared__ char lw[128 * 64 * 2];
  int tid = threadIdx.x;
  for (int j = tid; j < 576; j += 256) {
    int tap = j >> 6, c = j & 63;
    w9[tap][c] = pw[c * 9 + tap];
  }
  if (tid < 64) bb[tid] = pb[tid];
  for (int ch = tid; ch < 1024; ch += 256) {
    int r = ch >> 3, cg = ch & 7;
    int byte = (r * 128 + cg * 16) ^ ((r & 7) << 4);
    *(uint4*)(lw + byte) = *(const uint4*)((const short*)WTq + ch * 8);
  }
  __syncthreads();
  int blk = xcd_swz2048(blockIdx.x);
  int gid = blk * 256 + tid;
  int cg = gid & 15, pg = gid >> 4;
  int c0 = cg << 2;
  int w0 = (pg & 63) << 2, h = (pg >> 6) & 255, n = pg >> 14;
  int pbase = (n << 16) | (h << 8) | w0;
  int pl0 = (tid >> 4) << 2;  // local pixel base (0..60)
  float acc[4][4];
  {
    const float4 b4 = *(const float4*)&bb[c0];
#pragma unroll
    for (int px = 0; px < 4; px++) {
      acc[px][0] = b4.x; acc[px][1] = b4.y; acc[px][2] = b4.z; acc[px][3] = b4.w;
    }
  }
  float xc[4][4];
#pragma unroll
  for (int ky = 0; ky < 3; ky++) {
    int hh = h + ky - 1;
    if ((unsigned)hh >= 256u) continue;
    const float* xrow = X + (size_t)((n << 16) | (hh << 8)) * 64 + c0;
    float v[6][4];
#pragma unroll
    for (int dx = 0; dx < 6; dx++) {
      int ww = w0 + dx - 1;
      if ((unsigned)ww < 256u) ld4(xrow + (size_t)ww * 64, v[dx]);
      else { v[dx][0] = 0.f; v[dx][1] = 0.f; v[dx][2] = 0.f; v[dx][3] = 0.f; }
    }
    if (ky == 1) {
#pragma unroll
      for (int px = 0; px < 4; px++)
#pragma unroll
        for (int j = 0; j < 4; j++) xc[px][j] = v[px + 1][j];
    }
#pragma unroll
    for (int kx = 0; kx < 3; kx++) {
      const float4 wv = *(const float4*)&w9[ky * 3 + kx][c0];
#pragma unroll
      for (int px = 0; px < 4; px++) {
        acc[px][0] += wv.x * v[px + kx][0]; acc[px][1] += wv.y * v[px + kx][1];
        acc[px][2] += wv.z * v[px + kx][2]; acc[px][3] += wv.w * v[px + kx][3];
      }
    }
  }
  const float4 g4 = *(const float4*)&g[c0];
  const float4 b4 = *(const float4*)&b[c0];
#pragma unroll
  for (int px = 0; px < 4; px++) {
    float a[4];
#pragma unroll
    for (int j = 0; j < 4; j++) a[j] = xc[px][j] + acc[px][j];
    st4(A + (size_t)(pbase + px) * 64 + c0, a);
    float s = a[0] + a[1] + a[2] + a[3];
#pragma unroll
    for (int off = 8; off; off >>= 1) s += __shfl_xor(s, off);
    float mean = s * (1.f / 64.f);
    float d[4], q = 0.f;
#pragma unroll
    for (int j = 0; j < 4; j++) { d[j] = a[j] - mean; q += d[j] * d[j]; }
#pragma unroll
    for (int off = 8; off; off >>= 1) q += __shfl_xor(q, off);
    float inv = rsqrtf(q * (1.f / 64.f) + 1e-6f);
    float y[4] = {d[0] * inv * g4.x + b4.x, d[1] * inv * g4.y + b4.y,
                  d[2] * inv * g4.z + b4.z, d[3] * inv * g4.w + b4.w};
    st4(T + (size_t)(pbase + px) * 64 + c0, y);
    st4(&yt[pl0 + px][c0], y);
  }
  __syncthreads();
  // QKV MFMA: tile base is block-uniform blk*64
  int wid = tid >> 6, lane = tid & 63;
  int lr = lane & 15, lg = lane >> 4;
  size_t mbase = (size_t)blk * 64;
  short8v a0 = *(const short8v*)&yt[wid * 16 + lr][lg * 8];
  short8v a1 = *(const short8v*)&yt[wid * 16 + lr][32 + lg * 8];
#pragma unroll
  for (int nt = 0; nt < 8; nt++) {
    int col = nt * 16 + lr;
    float bv = col < 64 ? qbs[col] : vbias[col - 64];
    f32x4 acc4 = {bv, bv, bv, bv};
    int byte = (col * 128 + lg * 16) ^ ((col & 7) << 4);
    acc4 = __builtin_amdgcn_mfma_f32_16x16x32_bf16(a0, *(const short8v*)(lw + byte), acc4, 0, 0, 0);
    byte = (col * 128 + 64 + lg * 16) ^ ((col & 7) << 4);
    acc4 = __builtin_amdgcn_mfma_f32_16x16x32_bf16(a1, *(const short8v*)(lw + byte), acc4, 0, 0, 0);
#pragma unroll
    for (int j = 0; j < 4; j++) {
      size_t pix = mbase + wid * 16 + lg * 4 + j;
      if (col < 64) Qb[pix * 64 + col] = __float2bfloat16(acc4[j]);
      else          Vb[pix * 64 + (col - 64)] = __float2bfloat16(acc4[j]);
    }
  }
}

// ---- merged weight prep ----
__global__ void k_prep(const float* __restrict__ qkvw, const float* __restrict__ qkvb,
                       const float* __restrict__ wow, const float* __restrict__ f2w,
                       const float* __restrict__ f1w, const float* __restrict__ f1b,
                       const float* __restrict__ pww,
                       bf16* __restrict__ WTq, bf16* __restrict__ WTo,
                       bf16* __restrict__ WT2, bf16* __restrict__ WTf1,
                       float* __restrict__ qbs, float* __restrict__ bc) {
  int t = blockIdx.x * 256 + threadIdx.x;
  if (t < 8192) {
    int r = t >> 6, k = t & 63;
    int src = r < 64 ? r : r + 64;
    float v = qkvw[k * 192 + src];
    if (r < 64) v *= 0.125f;
    WTq[t] = __float2bfloat16(v);
  } else if (t < 12288) {
    int t2 = t - 8192;
    int r = t2 >> 6, k = t2 & 63;
    WTo[t2] = __float2bfloat16(wow[k * 64 + r]);
  } else if (t < 20480) {
    int t2 = t - 12288;
    int r = t2 >> 7, k = t2 & 127;
    WT2[t2] = __float2bfloat16(f2w[k * 64 + r]);
  } else if (t < 28672) {
    int t2 = t - 20480;                    // WTf1 rows 0..127 = W1b^T
    int r = t2 >> 6, k = t2 & 63;
    WTf1[t2] = __float2bfloat16(f1w[k * 256 + 128 + r]);
  } else if (t < 36864) {                  // WTf1 rows 128..255 = (W1a@pw^T)^T
    int t2 = t - 28672;
    int o = t2 & 127, k = t2 >> 7;
    float acc = 0.f;
    for (int j = 0; j < 128; j++) acc += f1w[k * 256 + j] * pww[o * 128 + j];
    WTf1[(128 + o) * 64 + k] = __float2bfloat16(acc);
  } else if (t < 36992) {                  // bc = b1a @ pw^T
    int o = t - 36864;
    float bv = 0.f;
    for (int j = 0; j < 128; j++) bv += f1b[j] * pww[o * 128 + j];
    bc[o] = bv;
  }
  if (t < 64) qbs[t] = qkvb[t] * 0.125f;
}

// ---- fused wo GEMM + res + LN2 + FC1 GEMM (LDS-staged weights) ----
__global__ void __launch_bounds__(256) k_wo_ln_fc1(const bf16* __restrict__ In,
                                                   const bf16* __restrict__ WTo,
                                                   const float* __restrict__ wob,
                                                   const float* __restrict__ Res,
                                                   float* __restrict__ Xo,
                                                   const float* __restrict__ g,
                                                   const float* __restrict__ b,
                                                   const bf16* __restrict__ WTf1,
                                                   const float* __restrict__ b1,
                                                   const float* __restrict__ b2,
                                                   bf16* __restrict__ VH,
                                                   bf16* __restrict__ PWO) {
  __shared__ char lwo[64 * 64 * 2];
  __shared__ char lf1[256 * 64 * 2];
  __shared__ float xs[16][68];
  __shared__ bf16 a2t[16][72];
  int tid = threadIdx.x;
  for (int ch = tid; ch < 512; ch += 256) {
    int r = ch >> 3, cg = ch & 7;
    int byte = (r * 128 + cg * 16) ^ ((r & 7) << 4);
    *(uint4*)(lwo + byte) = *(const uint4*)((const short*)WTo + ch * 8);
  }
  for (int ch = tid; ch < 2048; ch += 256) {
    int r = ch >> 3, cg = ch & 7;
    int byte = (r * 128 + cg * 16) ^ ((r & 7) << 4);
    *(uint4*)(lf1 + byte) = *(const uint4*)((const short*)WTf1 + ch * 8);
  }
  __syncthreads();
  int wid = tid >> 6, lane = tid & 63;
  int lr = lane & 15, lg = lane >> 4;
  int col_o = wid * 16 + lr;
  int mb = blockIdx.x * 128;
  int row2 = tid >> 4, cq = (tid & 15) << 2;
  const float4 g4 = *(const float4*)&g[cq];
  const float4 b4 = *(const float4*)&b[cq];
  float bvo = wob[col_o];
  for (int ms = 0; ms < 8; ms++) {
    int m0 = mb + ms * 16;
    {
      short8v a0 = *(const short8v*)((const short*)In + (size_t)(m0 + lr) * 64 + lg * 8);
      short8v a1 = *(const short8v*)((const short*)In + (size_t)(m0 + lr) * 64 + 32 + lg * 8);
      f32x4 acc = {bvo, bvo, bvo, bvo};
      int byte = (col_o * 128 + lg * 16) ^ ((col_o & 7) << 4);
      acc = __builtin_amdgcn_mfma_f32_16x16x32_bf16(a0, *(const short8v*)(lwo + byte), acc, 0, 0, 0);
      byte = (col_o * 128 + 64 + lg * 16) ^ ((col_o & 7) << 4);
      acc = __builtin_amdgcn_mfma_f32_16x16x32_bf16(a1, *(const short8v*)(lwo + byte), acc, 0, 0, 0);
#pragma unroll
      for (int j = 0; j < 4; j++) {
        float v = acc[j] + Res[(size_t)(m0 + lg * 4 + j) * 64 + col_o];
        Xo[(size_t)(m0 + lg * 4 + j) * 64 + col_o] = v;
        xs[lg * 4 + j][col_o] = v;
      }
    }
    __syncthreads();
    {
      float a4[4] = {xs[row2][cq], xs[row2][cq + 1], xs[row2][cq + 2], xs[row2][cq + 3]};
      float s = a4[0] + a4[1] + a4[2] + a4[3];
#pragma unroll
      for (int off = 8; off; off >>= 1) s += __shfl_xor(s, off);
      float mean = s * (1.f / 64.f);
      float d[4], q = 0.f;
#pragma unroll
      for (int j = 0; j < 4; j++) { d[j] = a4[j] - mean; q += d[j] * d[j]; }
#pragma unroll
      for (int off = 8; off; off >>= 1) q += __shfl_xor(q, off);
      float inv = rsqrtf(q * (1.f / 64.f) + 1e-6f);
      float y[4] = {d[0] * inv * g4.x + b4.x, d[1] * inv * g4.y + b4.y,
                    d[2] * inv * g4.z + b4.z, d[3] * inv * g4.w + b4.w};
      st4(&a2t[row2][cq], y);
    }
    __syncthreads();
    {
      short8v f0 = *(const short8v*)&a2t[lr][lg * 8];
      short8v f1 = *(const short8v*)&a2t[lr][32 + lg * 8];
#pragma unroll
      for (int t = 0; t < 4; t++) {
        int nt = wid * 4 + t;
        int col = nt * 16 + lr;
        float bv = col < 128 ? b1[col] : b2[col - 128];
        f32x4 acc = {bv, bv, bv, bv};
        int byte = (col * 128 + lg * 16) ^ ((col & 7) << 4);
        acc = __builtin_amdgcn_mfma_f32_16x16x32_bf16(f0, *(const short8v*)(lf1 + byte), acc, 0, 0, 0);
        byte = (col * 128 + 64 + lg * 16) ^ ((col & 7) << 4);
        acc = __builtin_amdgcn_mfma_f32_16x16x32_bf16(f1, *(const short8v*)(lf1 + byte), acc, 0, 0, 0);
#pragma unroll
        for (int j = 0; j < 4; j++) {
          size_t pix = m0 + lg * 4 + j;
          if (col < 128) VH[pix * 128 + col] = __float2bfloat16(acc[j]);
          else           PWO[pix * 128 + (col - 128)] = __float2bfloat16(acc[j]);
        }
      }
    }
    __syncthreads();
  }
}

// ---- fused GLU-dw + gelu*VH + fc2 GEMM + residual ----
// 128-px blocks, XCD-swizzled; LDS = 53760B (3 blocks/CU)
__global__ void __launch_bounds__(256) k_glu_fc2(const bf16* __restrict__ PWO,
                                                 const bf16* __restrict__ VH,
                                                 const float* __restrict__ wt,
                                                 const float* __restrict__ bs,
                                                 const bf16* __restrict__ WT2,
                                                 const float* __restrict__ f2b,
                                                 float* __restrict__ X) {
  __shared__ float wd[9][128];
  __shared__ char gts[128 * 256];   // gt[128][128] bf16, XOR-swizzled
  __shared__ char lw2[64 * 128 * 2];
  int tid = threadIdx.x;
  for (int j = tid; j < 1152; j += 256) {
    int tap = j >> 7, c = j & 127;
    wd[tap][c] = wt[c * 9 + tap];
  }
  for (int ch = tid; ch < 1024; ch += 256) {
    int r = ch >> 4, cg = ch & 15;
    int byte = (r * 256 + cg * 16) ^ ((r & 7) << 4);
    *(uint4*)(lw2 + byte) = *(const uint4*)((const short*)WT2 + ch * 8);
  }
  __syncthreads();
  int blk = xcd_swz1024(blockIdx.x);  // 1024 = (n*256 + h)*2 + half
  int w0 = (blk & 1) * 128, h = (blk >> 1) & 255, n = blk >> 9;
  int pbase = (n << 16) | (h << 8) | w0;
  int cg = tid & 31, c0 = cg << 2;
  int pg = tid >> 5;               // 0..7
  const float4 bb4 = *(const float4*)&bs[c0];
#pragma unroll
  for (int pass = 0; pass < 4; pass++) {
    int wb = w0 + pass * 32 + pg * 4;  // this thread's 4-px base
    // prefetch VH early (independent of conv chain)
    float vh[4][4];
#pragma unroll
    for (int px = 0; px < 4; px++)
      ld4(VH + (size_t)(pbase + pass * 32 + pg * 4 + px) * 128 + c0, vh[px]);
    float acc[4][4];
#pragma unroll
    for (int px = 0; px < 4; px++) {
      acc[px][0] = bb4.x; acc[px][1] = bb4.y; acc[px][2] = bb4.z; acc[px][3] = bb4.w;
    }
#pragma unroll
    for (int ky = 0; ky < 3; ky++) {
      int hh = h + ky - 1;
      if ((unsigned)hh >= 256u) continue;
      const bf16* prow = PWO + (size_t)((n << 16) | (hh << 8)) * 128 + c0;
      float v[6][4];
#pragma unroll
      for (int dx = 0; dx < 6; dx++) {
        int ww = wb + dx - 1;
        if ((unsigned)ww < 256u) ld4(prow + (size_t)ww * 128, v[dx]);
        else { v[dx][0] = 0.f; v[dx][1] = 0.f; v[dx][2] = 0.f; v[dx][3] = 0.f; }
      }
#pragma unroll
      for (int kx = 0; kx < 3; kx++) {
        const float4 wv = *(const float4*)&wd[ky * 3 + kx][c0];
#pragma unroll
        for (int px = 0; px < 4; px++) {
          acc[px][0] += wv.x * v[px + kx][0]; acc[px][1] += wv.y * v[px + kx][1];
          acc[px][2] += wv.z * v[px + kx][2]; acc[px][3] += wv.w * v[px + kx][3];
        }
      }
    }
#pragma unroll
    for (int px = 0; px < 4; px++) {
      int pl = pass * 32 + pg * 4 + px;
      float o[4];
#pragma unroll
      for (int j = 0; j < 4; j++) {
        float x = acc[px][j];
        float ge = 0.5f * x * (1.f + erff(x * 0.70710678118f));
        o[j] = ge * vh[px][j];
      }
      int byte = (pl * 256 + c0 * 2) ^ ((pl & 7) << 4);
      st4((bf16*)(gts + byte), o);
    }
  }
  __syncthreads();
  // fc2: K=128, N=64; 8 m-tiles, wave handles m-tiles {wid, wid+4}
  int wid = tid >> 6, lane = tid & 63;
  int lr = lane & 15, lg = lane >> 4;
#pragma unroll
  for (int mi = 0; mi < 2; mi++) {
    int mt = wid + mi * 4;
    int m0 = mt * 16;
    short8v a[4];
#pragma unroll
    for (int ks = 0; ks < 4; ks++) {
      int row = m0 + lr;
      int byte = (row * 256 + ks * 64 + lg * 16) ^ ((row & 7) << 4);
      a[ks] = *(const short8v*)(gts + byte);
    }
#pragma unroll
    for (int nt = 0; nt < 4; nt++) {
      int col = nt * 16 + lr;
      float bv = f2b[col];
      f32x4 acc = {bv, bv, bv, bv};
#pragma unroll
      for (int ks = 0; ks < 4; ks++) {
        int byte = (col * 256 + ks * 64 + lg * 16) ^ ((col & 7) << 4);
        acc = __builtin_amdgcn_mfma_f32_16x16x32_bf16(a[ks], *(const short8v*)(lw2 + byte), acc, 0, 0, 0);
      }
#pragma unroll
      for (int j = 0; j < 4; j++) {
        size_t pix = pbase + m0 + lg * 4 + j;
        X[pix * 64 + col] += acc[j];
      }
    }
  }
}

// ---- 8x8 block means of LN1 (f32, exact routing path) ----
__global__ void k_pool8(const float* __restrict__ T, float* __restrict__ Y8) {
  int b = blockIdx.x;
  int c = threadIdx.x;
  int bx = b & 31, by = (b >> 5) & 31, n = b >> 10;
  float acc = 0.f;
  for (int r = 0; r < 8; r++)
    for (int s = 0; s < 8; s++) {
      int p = (n << 16) | ((by * 8 + r) << 8) | (bx * 8 + s);
      acc += T[(size_t)p * 64 + c];
    }
  Y8[(size_t)b * 64 + c] = acc * (1.f / 64.f);
}

// ---- fused window-mean + q/k projection ----
__global__ void __launch_bounds__(256) k_qkwin2(const float* __restrict__ Y8,
                                                const float* __restrict__ qw,
                                                const float* __restrict__ qb,
                                                float* __restrict__ QW,
                                                float* __restrict__ KW) {
  __shared__ float ym[4][68];
  int blk = blockIdx.x;
  int sel = blk >> 5;
  int r0 = (blk & 31) * 4;
  int tid = threadIdx.x;
  {
    int rl = tid >> 6, c = tid & 63;
    int row = r0 + rl;
    int n = row >> 6, win = row & 63;
    int wi = win >> 3, wj = win & 7;
    float acc = 0.f;
    for (int ti = 0; ti < 4; ti++)
      for (int tj = 0; tj < 4; tj++) {
        int y8 = (n * 32 + wi * 4 + ti) * 32 + wj * 4 + tj;
        acc += Y8[(size_t)y8 * 64 + c];
      }
    ym[rl][c] = acc * (1.f / 16.f);
  }
  __syncthreads();
  int rl = tid >> 6, c = tid & 63;
  int row = r0 + rl;
  int colg = sel * 64 + c;
  float acc = qb[colg];
  for (int k = 0; k < 64; k++) acc += ym[rl][k] * qw[k * 192 + colg];
  (sel ? KW : QW)[(size_t)row * 64 + c] = acc;
}

__global__ void k_kvp(const float* __restrict__ Y8, const float* __restrict__ qw,
                      const float* __restrict__ qb, float* __restrict__ KVP) {
  int t = blockIdx.x * blockDim.x + threadIdx.x;
  if (t >= 262144) return;
  int c2 = t & 127, tok = (t >> 7) & 15, win = (t >> 11) & 63, n = t >> 17;
  int wi = win >> 3, wj = win & 7, ti = tok >> 2, tj = tok & 3;
  int y8 = (n * 32 + wi * 4 + ti) * 32 + wj * 4 + tj;
  const float* y = Y8 + (size_t)y8 * 64;
  int col = 64 + c2;
  float acc = qb[col];
  for (int k = 0; k < 64; k++) acc += y[k] * qw[k * 192 + col];
  KVP[t] = acc;
}

// ---- routing: top-4 ----
__global__ void __launch_bounds__(64) k_route(const float* __restrict__ QW,
                                              const float* __restrict__ KW,
                                              int* __restrict__ RIDX) {
  __shared__ float kk[64][65];
  __shared__ float qq[64];
  int b = blockIdx.x;
  int lane = threadIdx.x;
  int n = b >> 6;
  qq[lane] = QW[(size_t)b * 64 + lane];
  for (int r = 0; r < 64; r++) kk[r][lane] = KW[(size_t)(n * 64 + r) * 64 + lane];
  __syncthreads();
  float t = 0.f;
  for (int c = 0; c < 64; c++) t += qq[c] * kk[lane][c];
  t *= 0.125f;
  int o0 = 0, o1 = 0, o2 = 0, o3 = 0;
#pragma unroll
  for (int j = 0; j < 4; j++) {
    float v = t; int idx = lane;
#pragma unroll
    for (int off = 32; off; off >>= 1) {
      float ov = __shfl_xor(v, off);
      int oi = __shfl_xor(idx, off);
      if (ov > v || (ov == v && oi < idx)) { v = ov; idx = oi; }
    }
    if (j == 0) o0 = idx; else if (j == 1) o1 = idx;
    else if (j == 2) o2 = idx; else o3 = idx;
    if (lane == idx) t = -1e30f;
  }
  if (lane == 0) {
    int* o = RIDX + (size_t)b * 4;
    o[0] = o0; o[1] = o1; o[2] = o2; o[3] = o3;
  }
}

// ---- MFMA attention -> bf16 output ----
__global__ void __launch_bounds__(256) k_attn_mf(const bf16* __restrict__ Qb,
                                                 const float* __restrict__ KVP,
                                                 const int* __restrict__ RIDX,
                                                 bf16* __restrict__ Sbf) {
  __shared__ bf16 ks[64][72];
  __shared__ bf16 vt[64][72];
  __shared__ bf16 pa[4][16][72];
  __shared__ float ldn[4][16];
  __shared__ int idx[4];
  int blk = blockIdx.x;
  int part = blk & 3, bw = blk >> 2;
  int n = bw >> 6, win = bw & 63;
  int tid = threadIdx.x;
  if (tid < 4) idx[tid] = RIDX[bw * 4 + tid];
  __syncthreads();
  {
    int tok = tid & 63;
    const float* src = KVP + ((size_t)(n * 64 + idx[tok >> 4]) * 16 + (tok & 15)) * 128;
    for (int cq = tid >> 6; cq < 16; cq += 4) {
      int c0 = cq * 4;
      const float4 k4 = *(const float4*)&src[c0];
      *(uint2*)&ks[tok][c0] = pk4(k4.x, k4.y, k4.z, k4.w);
      const float4 v4 = *(const float4*)&src[64 + c0];
      vt[c0 + 0][tok] = __float2bfloat16(v4.x);
      vt[c0 + 1][tok] = __float2bfloat16(v4.y);
      vt[c0 + 2][tok] = __float2bfloat16(v4.z);
      vt[c0 + 3][tok] = __float2bfloat16(v4.w);
    }
  }
  __syncthreads();
  int w = tid >> 6, lane = tid & 63;
  int lr = lane & 15, lg = lane >> 4;
  int wi = win >> 3, wj = win & 7;
  for (int it = 0; it < 4; it++) {
    int qbase = part * 256 + w * 64 + it * 16;
    int q_b = qbase + lr;
    int pix_b = (n << 16) | ((wi * 32 + (q_b >> 5)) << 8) | (wj * 32 + (q_b & 31));
    short8v qf0 = *(const short8v*)((const short*)Qb + (size_t)pix_b * 64 + lg * 8);
    short8v qf1 = *(const short8v*)((const short*)Qb + (size_t)pix_b * 64 + 32 + lg * 8);
    f32x4 p[4] = {{0,0,0,0},{0,0,0,0},{0,0,0,0},{0,0,0,0}};
#pragma unroll
    for (int mt = 0; mt < 4; mt++) {
      short8v a0 = *(const short8v*)&ks[mt * 16 + lr][lg * 8];
      p[mt] = __builtin_amdgcn_mfma_f32_16x16x32_bf16(a0, qf0, p[mt], 0, 0, 0);
    }
#pragma unroll
    for (int mt = 0; mt < 4; mt++) {
      short8v a1 = *(const short8v*)&ks[mt * 16 + lr][32 + lg * 8];
      p[mt] = __builtin_amdgcn_mfma_f32_16x16x32_bf16(a1, qf1, p[mt], 0, 0, 0);
    }
    float mx = -1e30f;
#pragma unroll
    for (int mt = 0; mt < 4; mt++)
#pragma unroll
      for (int j = 0; j < 4; j++) mx = fmaxf(mx, p[mt][j]);
    mx = fmaxf(mx, __shfl_xor(mx, 16));
    mx = fmaxf(mx, __shfl_xor(mx, 32));
    float e[4][4];
    float sum = 0.f;
#pragma unroll
    for (int mt = 0; mt < 4; mt++)
#pragma unroll
      for (int j = 0; j < 4; j++) { e[mt][j] = __expf(p[mt][j] - mx); sum += e[mt][j]; }
    sum += __shfl_xor(sum, 16);
    sum += __shfl_xor(sum, 32);
    if (lg == 0) ldn[w][lr] = sum;
#pragma unroll
    for (int mt = 0; mt < 4; mt++)
      *(uint2*)&pa[w][lr][mt * 16 + lg * 4] = pk4(e[mt][0], e[mt][1], e[mt][2], e[mt][3]);
    short8v pf0 = *(const short8v*)&pa[w][lr][lg * 8];
    short8v pf1 = *(const short8v*)&pa[w][lr][32 + lg * 8];
    f32x4 o4[4] = {{0,0,0,0},{0,0,0,0},{0,0,0,0},{0,0,0,0}};
#pragma unroll
    for (int nt = 0; nt < 4; nt++) {
      short8v v0 = *(const short8v*)&vt[nt * 16 + lr][lg * 8];
      o4[nt] = __builtin_amdgcn_mfma_f32_16x16x32_bf16(pf0, v0, o4[nt], 0, 0, 0);
    }
#pragma unroll
    for (int nt = 0; nt < 4; nt++) {
      short8v v1 = *(const short8v*)&vt[nt * 16 + lr][32 + lg * 8];
      o4[nt] = __builtin_amdgcn_mfma_f32_16x16x32_bf16(pf1, v1, o4[nt], 0, 0, 0);
    }
    float linv[4];
#pragma unroll
    for (int j = 0; j < 4; j++) linv[j] = 1.f / ldn[w][lg * 4 + j];
#pragma unroll
    for (int j = 0; j < 4; j++) {
      int q_o = qbase + lg * 4 + j;
      size_t pix_o = (n << 16) | ((wi * 32 + (q_o >> 5)) << 8) | (wj * 32 + (q_o & 31));
      bf16* op = Sbf + pix_o * 64 + lr;
#pragma unroll
      for (int nt = 0; nt < 4; nt++) op[nt * 16] = __float2bfloat16(o4[nt][j] * linv[j]);
    }
  }
}

// ---- LePE: 4 px/thread (XCD-swizzled); Sb = bf16(Sbf + dw5x5(V)) ----
__global__ void __launch_bounds__(256) k_lepe4(const bf16* __restrict__ V,
                                               const bf16* __restrict__ Sbf,
                                               bf16* __restrict__ Sb,
                                               const float* __restrict__ wt,
                                               const float* __restrict__ bs) {
  __shared__ float w5[25][68];
  __shared__ float bb[64];
  int tid = threadIdx.x;
  for (int j = tid; j < 1600; j += 256) {
    int tap = j >> 6, c = j & 63;
    w5[tap][c] = wt[c * 25 + tap];
  }
  if (tid < 64) bb[tid] = bs[tid];
  __syncthreads();
  int blk = xcd_swz2048(blockIdx.x);
  int gid = blk * 256 + tid;
  int cg = gid & 15, pg = gid >> 4;
  int c0 = cg << 2;
  int w0 = (pg & 63) << 2, h = (pg >> 6) & 255, n = pg >> 14;
  int pbase = (n << 16) | (h << 8) | w0;
  float acc[4][4];
  {
    const float4 b4 = *(const float4*)&bb[c0];
#pragma unroll
    for (int px = 0; px < 4; px++) {
      acc[px][0] = b4.x; acc[px][1] = b4.y; acc[px][2] = b4.z; acc[px][3] = b4.w;
    }
  }
#pragma unroll
  for (int ky = 0; ky < 5; ky++) {
    int hh = h + ky - 2;
    if ((unsigned)hh >= 256u) continue;
    const bf16* vrow = V + (size_t)((n << 16) | (hh << 8)) * 64 + c0;
    float v[8][4];
#pragma unroll
    for (int dx = 0; dx < 8; dx++) {
      int ww = w0 + dx - 2;
      if ((unsigned)ww < 256u) ld4(vrow + (size_t)ww * 64, v[dx]);
      else { v[dx][0] = 0.f; v[dx][1] = 0.f; v[dx][2] = 0.f; v[dx][3] = 0.f; }
    }
#pragma unroll
    for (int kx = 0; kx < 5; kx++) {
      const float4 wv = *(const float4*)&w5[ky * 5 + kx][c0];
#pragma unroll
      for (int px = 0; px < 4; px++) {
        acc[px][0] += wv.x * v[px + kx][0]; acc[px][1] += wv.y * v[px + kx][1];
        acc[px][2] += wv.z * v[px + kx][2]; acc[px][3] += wv.w * v[px + kx][3];
      }
    }
  }
#pragma unroll
  for (int px = 0; px < 4; px++) {
    float s4[4];
    ld4(Sbf + (size_t)(pbase + px) * 64 + c0, s4);
    float o[4] = {s4[0] + acc[px][0], s4[1] + acc[px][1],
                  s4[2] + acc[px][2], s4[3] + acc[px][3]};
    st4(Sb + (size_t)(pbase + px) * 64 + c0, o);
  }
}

extern "C" void kernel_launch(void* const* d_in, const int* in_sizes, int n_in,
                              void* d_out, int out_size, void* d_ws, size_t ws_size,
                              hipStream_t stream) {
  (void)in_sizes; (void)n_in; (void)out_size; (void)ws_size;
  const float* xin = (const float*)d_in[0];
  auto Wp = [&](int i) { return (const float*)d_in[i]; };
  char* ws = (char*)d_ws;
  const size_t MB = 1u << 20;
  float* X  = (float*)(ws + 0 * MB);
  float* A  = (float*)(ws + 32 * MB);
  float* T  = (float*)(ws + 64 * MB);
  char*  sm = ws + 128 * MB;
  size_t off = 0;
  auto alloc = [&](size_t bytes) {
    void* p = sm + off;
    off += (bytes + 255) & ~(size_t)255;
    return p;
  };
  float* Y8   = (float*)alloc(2 * 32 * 32 * 64 * 4);
  float* QW   = (float*)alloc(2 * 64 * 64 * 4);
  float* KW   = (float*)alloc(2 * 64 * 64 * 4);
  float* KVP  = (float*)alloc(2 * 64 * 16 * 128 * 4);
  int*  RIDX  = (int*)alloc(2 * 64 * 4 * 4);
  float* bc   = (float*)alloc(128 * 4);
  bf16* WTq   = (bf16*)alloc(128 * 64 * 2);
  bf16* WTo   = (bf16*)alloc(64 * 64 * 2);
  bf16* WT2   = (bf16*)alloc(64 * 128 * 2);
  bf16* WTf1  = (bf16*)alloc(256 * 64 * 2);
  float* qbs  = (float*)alloc(64 * 4);
  bf16* Vb   = (bf16*)(ws + 96 * MB);    // [P][64]
  bf16* Qb   = (bf16*)(ws + 112 * MB);   // [P][64]
  bf16* Sbf  = (bf16*)T;                 // [P][64]
  bf16* Sb   = (bf16*)(ws + 112 * MB);   // [P][64] (Qb dead after attn)
  bf16* VH   = (bf16*)A;                 // [P][128] (A consumed in-kernel)
  bf16* PWO  = (bf16*)T;                 // [P][128] (T/Sbf dead)

  k_in_tr<<<dim3(2048), dim3(256), 0, stream>>>(xin, X);
  for (int i = 0; i < 2; i++) {
    const float *posw = Wp(1) + i * 64 * 9, *posb = Wp(2) + i * 64;
    const float *l1g = Wp(3) + i * 64, *l1b = Wp(4) + i * 64;
    const float *qkvw = Wp(5) + i * 64 * 192, *qkvb = Wp(6) + i * 192;
    const float *lpw = Wp(7) + i * 64 * 25, *lpb = Wp(8) + i * 64;
    const float *wow = Wp(9) + i * 64 * 64, *wob = Wp(10) + i * 64;
    const float *l2g = Wp(11) + i * 64, *l2b = Wp(12) + i * 64;
    const float *f1w = Wp(13) + i * 64 * 256, *f1b = Wp(14) + i * 256;
    const float *pww = Wp(15) + i * 128 * 128;
    const float *dww = Wp(16) + i * 128 * 9, *dwb = Wp(17) + i * 128;
    const float *f2w = Wp(18) + i * 128 * 64, *f2b = Wp(19) + i * 64;

    k_prep<<<dim3(145), dim3(256), 0, stream>>>(qkvw, qkvb, wow, f2w, f1w, f1b, pww,
                                                WTq, WTo, WT2, WTf1, qbs, bc);
    k_pcln_qkv<<<dim3(2048), dim3(256), 0, stream>>>(
        X, A, T, posw, posb, l1g, l1b, WTq, qbs, qkvb + 128, Qb, Vb);
    k_pool8<<<dim3(2048), dim3(64), 0, stream>>>(T, Y8);
    k_qkwin2<<<dim3(64), dim3(256), 0, stream>>>(Y8, qkvw, qkvb, QW, KW);
    k_kvp<<<dim3(1024), dim3(256), 0, stream>>>(Y8, qkvw, qkvb, KVP);
    k_route<<<dim3(128), dim3(64), 0, stream>>>(QW, KW, RIDX);
    k_attn_mf<<<dim3(512), dim3(256), 0, stream>>>(Qb, KVP, RIDX, Sbf);
    k_lepe4<<<dim3(2048), dim3(256), 0, stream>>>(Vb, Sbf, Sb, lpw, lpb);
    k_wo_ln_fc1<<<dim3(Pp / 128), dim3(256), 0, stream>>>(
        Sb, WTo, wob, A, X, l2g, l2b, WTf1, f1b + 128, bc, VH, PWO);
    k_glu_fc2<<<dim3(1024), dim3(256), 0, stream>>>(PWO, VH, dww, dwb, WT2, f2b, X);
  }
  k_out<<<dim3(2048), dim3(256), 0, stream>>>(X, (float*)d_out);
}